// Round 1
// baseline (2411.768 us; speedup 1.0000x reference)
//
#include <hip/hip_runtime.h>

// PolicyAwareLSTM: 2-layer LSTM (4096 x 336, 32->64->32) + seq1-MHA (== two 32x32
// matmuls) + dense 32->64->24 head. fp32 throughout (no fp32 MFMA on CDNA4).
//
// Design: one gate-column of W1/U1 per thread in REGISTERS (broadcast LDS reads of
// activations), split-K layer-2 columns across thread halves. 512 blocks x 8 rows,
// 256 threads, 2 blocks/CU.

#define B_TOTAL 4096
#define T_STEPS 336
#define NF      32     // input features
#define U1N     64     // layer-1 units
#define G1      256    // 4*U1N
#define U2N     32     // layer-2 units
#define G2      128    // 4*U2N
#define RROWS   8      // batch rows per block
#define NT      256    // threads per block

__device__ __forceinline__ float fast_sigmoid(float x) {
    return __fdividef(1.0f, 1.0f + __expf(-x));
}

__device__ __forceinline__ float fast_tanh(float x) {
    float ax = fabsf(x);
    float e  = __expf(-2.0f * ax);
    float r  = __fdividef(1.0f - e, 1.0f + e);
    return __builtin_copysignf(r, x);
}

__global__ __launch_bounds__(NT, 2) void lstm_fused(
    const float* __restrict__ x,
    const float* __restrict__ W1, const float* __restrict__ U1, const float* __restrict__ b1,
    const float* __restrict__ W2, const float* __restrict__ U2, const float* __restrict__ b2,
    const float* __restrict__ Wv, const float* __restrict__ bv,
    const float* __restrict__ Wo, const float* __restrict__ bo,
    const float* __restrict__ Wd1, const float* __restrict__ bd1,
    const float* __restrict__ Wd2, const float* __restrict__ bd2,
    float* __restrict__ out)
{
    __shared__ float x_sh[2][RROWS][NF];      // double-buffered input slice
    __shared__ float h1_sh[RROWS][U1N];
    __shared__ float h2_sh[RROWS][U2N];
    __shared__ float z1_sh[RROWS][G1];
    __shared__ float z2p_sh[RROWS][2][G2];    // split-K partials for layer 2
    __shared__ float t0_sh[RROWS][U2N];       // head temp (v, then o)
    __shared__ float d1_sh[RROWS][64];        // head temp (dense1)

    const int tid = threadIdx.x;
    const int r0  = blockIdx.x * RROWS;

    // ---- load weight columns into registers (coalesced: lanes -> consecutive cols)
    float w1c[NF], u1c[U1N];
    #pragma unroll
    for (int j = 0; j < NF; ++j)  w1c[j] = W1[j * G1 + tid];
    #pragma unroll
    for (int j = 0; j < U1N; ++j) u1c[j] = U1[j * G1 + tid];
    const float b1r = b1[tid];

    const int g2   = tid & (G2 - 1);
    const int half = tid >> 7;                // 0: K-elems [0..32)/[0..16), 1: rest
    float w2c[32], u2c[16];
    #pragma unroll
    for (int j = 0; j < 32; ++j) w2c[j] = W2[(half * 32 + j) * G2 + g2];
    #pragma unroll
    for (int j = 0; j < 16; ++j) u2c[j] = U2[(half * 16 + j) * G2 + g2];
    const float b2r = (half == 0) ? b2[g2] : 0.0f;

    // ---- zero initial states
    ((float*)h1_sh)[tid]      = 0.0f;         // RROWS*U1N = 512
    ((float*)h1_sh)[NT + tid] = 0.0f;
    ((float*)h2_sh)[tid]      = 0.0f;         // RROWS*U2N = 256
    float c1a0 = 0.0f, c1a1 = 0.0f;           // cell state L1: 2 units/thread
    float c2a  = 0.0f;                        // cell state L2: 1 unit/thread

    // ---- preload x for t=0
    const int xr = tid >> 5, xj = tid & 31;   // 8 rows x 32 feats = 256 threads
    const int xbase = (r0 + xr) * (T_STEPS * NF) + xj;
    x_sh[0][xr][xj] = x[xbase];
    __syncthreads();

    for (int t = 0; t < T_STEPS; ++t) {
        const int buf = t & 1;

        // prefetch next step's x slice (clamped at the end; extra load is harmless)
        const int tn = (t + 1 < T_STEPS) ? (t + 1) : (T_STEPS - 1);
        const float xnext = x[xbase + tn * NF];

        // ---- phase 1: z1[r][tid] = b1 + x_t@W1 + h1@U1  (broadcast LDS reads)
        #pragma unroll
        for (int r = 0; r < RROWS; ++r) {
            float acc = b1r;
            #pragma unroll
            for (int j = 0; j < NF; ++j)  acc = fmaf(x_sh[buf][r][j], w1c[j], acc);
            #pragma unroll
            for (int j = 0; j < U1N; ++j) acc = fmaf(h1_sh[r][j], u1c[j], acc);
            z1_sh[r][tid] = acc;
        }
        __syncthreads();

        // ---- gate 1: 2 units per thread (Keras order i,f,g,o)
        {
            #pragma unroll
            for (int k = 0; k < 2; ++k) {
                const int flat = tid + k * NT;
                const int r = flat >> 6, u = flat & 63;
                const float zi = z1_sh[r][u];
                const float zf = z1_sh[r][64 + u];
                const float zg = z1_sh[r][128 + u];
                const float zo = z1_sh[r][192 + u];
                const float ig = fast_sigmoid(zi);
                const float fg = fast_sigmoid(zf);
                const float gg = fast_tanh(zg);
                const float og = fast_sigmoid(zo);
                float cprev = (k == 0) ? c1a0 : c1a1;
                const float c = fmaf(fg, cprev, ig * gg);
                if (k == 0) c1a0 = c; else c1a1 = c;
                h1_sh[r][u] = og * fast_tanh(c);
            }
        }
        __syncthreads();

        // ---- phase 2: z2 partials, split-K across thread halves
        #pragma unroll
        for (int r = 0; r < RROWS; ++r) {
            float acc = b2r;
            #pragma unroll
            for (int j = 0; j < 32; ++j) acc = fmaf(h1_sh[r][half * 32 + j], w2c[j], acc);
            #pragma unroll
            for (int j = 0; j < 16; ++j) acc = fmaf(h2_sh[r][half * 16 + j], u2c[j], acc);
            z2p_sh[r][half][g2] = acc;
        }
        __syncthreads();

        // ---- gate 2: 1 unit per thread
        {
            const int r = tid >> 5, u = tid & 31;
            const float zi = z2p_sh[r][0][u]      + z2p_sh[r][1][u];
            const float zf = z2p_sh[r][0][32 + u] + z2p_sh[r][1][32 + u];
            const float zg = z2p_sh[r][0][64 + u] + z2p_sh[r][1][64 + u];
            const float zo = z2p_sh[r][0][96 + u] + z2p_sh[r][1][96 + u];
            const float ig = fast_sigmoid(zi);
            const float fg = fast_sigmoid(zf);
            const float gg = fast_tanh(zg);
            const float og = fast_sigmoid(zo);
            c2a = fmaf(fg, c2a, ig * gg);
            h2_sh[r][u] = og * fast_tanh(c2a);
        }
        // park prefetched x into the other buffer (read was >=1 barrier ago)
        x_sh[1 - buf][xr][xj] = xnext;
        __syncthreads();
    }

    // ---- head: v = h2@Wv+bv ; o = v@Wo+bo ; d1 = relu(o@Wd1+bd1) ; out = d1@Wd2+bd2
    {
        const int r = tid >> 5, cidx = tid & 31;
        float acc = bv[cidx];
        #pragma unroll
        for (int j = 0; j < 32; ++j) acc = fmaf(h2_sh[r][j], Wv[j * 32 + cidx], acc);
        t0_sh[r][cidx] = acc;              // v
        __syncthreads();

        float acc2 = bo[cidx];
        #pragma unroll
        for (int j = 0; j < 32; ++j) acc2 = fmaf(t0_sh[r][j], Wo[j * 32 + cidx], acc2);
        __syncthreads();                   // all reads of v done
        t0_sh[r][cidx] = acc2;             // o
        __syncthreads();

        #pragma unroll
        for (int k = 0; k < 2; ++k) {
            const int c64 = cidx + k * 32;
            float a = bd1[c64];
            #pragma unroll
            for (int j = 0; j < 32; ++j) a = fmaf(t0_sh[r][j], Wd1[j * 64 + c64], a);
            d1_sh[r][c64] = fmaxf(a, 0.0f);
        }
        __syncthreads();

        if (tid < RROWS * 24) {
            const int rr = tid / 24, cc = tid - rr * 24;
            float a = bd2[cc];
            #pragma unroll
            for (int j = 0; j < 64; ++j) a = fmaf(d1_sh[rr][j], Wd2[j * 24 + cc], a);
            out[(r0 + rr) * 24 + cc] = a;
        }
    }
}

extern "C" void kernel_launch(void* const* d_in, const int* in_sizes, int n_in,
                              void* d_out, int out_size, void* d_ws, size_t ws_size,
                              hipStream_t stream) {
    const float* x   = (const float*)d_in[0];
    const float* W1  = (const float*)d_in[1];
    const float* U1  = (const float*)d_in[2];
    const float* b1  = (const float*)d_in[3];
    const float* W2  = (const float*)d_in[4];
    const float* U2  = (const float*)d_in[5];
    const float* b2  = (const float*)d_in[6];
    // d_in[7..10] = Wq, bq, Wk, bk — dead: softmax over a length-1 axis is identically 1
    const float* Wv  = (const float*)d_in[11];
    const float* bv  = (const float*)d_in[12];
    const float* Wo  = (const float*)d_in[13];
    const float* bo  = (const float*)d_in[14];
    const float* Wd1 = (const float*)d_in[15];
    const float* bd1 = (const float*)d_in[16];
    const float* Wd2 = (const float*)d_in[17];
    const float* bd2 = (const float*)d_in[18];
    float* outp = (float*)d_out;

    hipLaunchKernelGGL(lstm_fused, dim3(B_TOTAL / RROWS), dim3(NT), 0, stream,
                       x, W1, U1, b1, W2, U2, b2, Wv, bv, Wo, bo,
                       Wd1, bd1, Wd2, bd2, outp);
}